// Round 10
// baseline (168.850 us; speedup 1.0000x reference)
//
#include <hip/hip_runtime.h>
#include <hip/hip_bf16.h>

// HyperbolicMessagePassing: N=50000, E=600000, D=128.
// out = expmap0( MLP2( mean_scatter( MLP1(logmap0(x))[src] -> dst ) ) )
// Message MLP depends only on src -> compute per-node (50k rows not 600k).
// R19 = R17 base (155.6us best) + TRUE XCD-local replicated CSR fill:
//   R16's replication used blockIdx&7 (undefined mapping -> no locality) and
//   8x metadata tax. Now: replica = real XCC_ID (s_getreg, m09-verified), so
//   all atomics/stores of a replica come from ONE XCD -> no line migration.
//   Lean replicas: 8 slots/replica (u16, 16B window), unpadded counts,
//   exact rare spill list for overflow. Stage2 = R17 serial-row structure,
//   16-deep gather halves, window tails read from registers.

#define DD 128
#define CAP8 8   // slots per node per XCD replica (Poisson(1.5) typical)
#define CAPS 64  // global spill slots per node (exact overflow path)
#define NR 8     // replicas = XCDs

typedef __attribute__((ext_vector_type(8))) short short8;
typedef __attribute__((ext_vector_type(8))) unsigned short u16x8;
typedef __attribute__((ext_vector_type(4))) float f32x4;

__device__ __forceinline__ unsigned short f2bf(float f) {
  unsigned u = __float_as_uint(f);
  u += 0x7fffu + ((u >> 16) & 1u);  // round-to-nearest-even
  return (unsigned short)(u >> 16);
}
__device__ __forceinline__ float bf2f(short h) {
  return __uint_as_float(((unsigned)(unsigned short)h) << 16);
}

// blocks [0,32): pack 4 W (fp32 128x128) into bf16 MFMA B-frag-linear order.
// blocks [32,..): zero degv8[8N] + degS[N] (contiguous 9N ints)
__global__ void k_init(const float* __restrict__ w1, const float* __restrict__ w2,
                       const float* __restrict__ w3, const float* __restrict__ w4,
                       unsigned short* __restrict__ P, int* __restrict__ degz, int N) {
  if (blockIdx.x < 32) {
    int idx = blockIdx.x * 256 + threadIdx.x;  // 4 matrices x 2048 (frag,lane)
    int m = idx >> 11;
    int id = idx & 2047;
    int f = id >> 6, l = id & 63;
    int cc = f >> 2, s = f & 3, q = l >> 4, n15 = l & 15;
    const float* W = (m == 0) ? w1 : (m == 1) ? w2 : (m == 2) ? w3 : w4;
    const float* wp = W + (s * 32 + q * 8) * DD + cc * 16 + n15;
    unsigned short* op = P + (size_t)m * 16384 + (size_t)id * 8;
#pragma unroll
    for (int j = 0; j < 8; ++j) op[j] = f2bf(wp[j * DD]);
  } else {
    int i = (blockIdx.x - 32) * 256 + threadIdx.x;
    if (i < 9 * N) degz[i] = 0;  // degv8 (8N) then degS (N)
  }
}

// stage1: blocks [0,ne) = XCD-local replicated edge fill (dispatched FIRST,
//         overlaps MLP); blocks [ne,..) = logmap0 + MLP1 -> node_msg.
__global__ __launch_bounds__(256) void k_stage1(
    const float* __restrict__ x, const int* __restrict__ ei,
    const unsigned short* __restrict__ Pa, const float* __restrict__ ba,
    const unsigned short* __restrict__ Pb, const float* __restrict__ bb,
    unsigned short* __restrict__ node_msg, int* __restrict__ degv8,
    int* __restrict__ degS, unsigned short* __restrict__ ebuf8,
    unsigned short* __restrict__ ebufS, int N, int E, int ne) {
  __shared__ unsigned short As[32 * 136];  // row stride 136 shorts
  const int tid = threadIdx.x;

  if (blockIdx.x < ne) {  // ---- edge-fill: 1024 edges/block, 4/thread ----
    unsigned xcc;
    asm volatile("s_getreg_b32 %0, hwreg(HW_REG_XCC_ID)" : "=s"(xcc));
    const int rg = (int)(xcc & (NR - 1));  // THIS block's physical XCD
    int eb_[4], d_[4], s_[4], p_[4];
#pragma unroll
    for (int k = 0; k < 4; ++k) {
      int e = blockIdx.x * 1024 + k * 256 + tid;
      eb_[k] = e;
      if (e < E) {
        d_[k] = ei[e];       // edge_index[0] = dst
        s_[k] = ei[E + e];   // edge_index[1] = src
      }
    }
#pragma unroll
    for (int k = 0; k < 4; ++k)
      if (eb_[k] < E)
        p_[k] = atomicAdd(degv8 + (size_t)rg * N + d_[k], 1);
#pragma unroll
    for (int k = 0; k < 4; ++k)
      if (eb_[k] < E) {
        if (p_[k] < CAP8) {
          ebuf8[((size_t)rg * N + d_[k]) * CAP8 + p_[k]] = (unsigned short)s_[k];
        } else {  // rare overflow: exact global spill
          int ps = atomicAdd(degS + d_[k], 1);
          if (ps < CAPS)
            ebufS[(size_t)d_[k] * CAPS + ps] = (unsigned short)s_[k];
        }
      }
    return;
  }

  const int lane = tid & 63;
  const int wv = tid >> 6;  // 0..3
  const int rt = wv >> 1;   // row-tile 0..1
  const int ct = wv & 1;    // col-tile 0..1
  const int q = lane >> 4;
  const int n15 = lane & 15;
  const int row0 = (blockIdx.x - ne) * 32;
  const int g = (wv << 2) | q;  // staging group 0..15

  // ---- stage A tile: logmap0, group g rows g*2..g*2+1, 16 lanes/row ----
  f32x4 xa[2][2];
#pragma unroll
  for (int i = 0; i < 2; ++i) {
    const int grow = row0 + g * 2 + i;
    if (grow < N) {
      const f32x4* p = (const f32x4*)(x + (size_t)grow * DD + n15 * 8);
      xa[i][0] = p[0];
      xa[i][1] = p[1];
    } else {
      xa[i][0] = (f32x4){0.f, 0.f, 0.f, 0.f};
      xa[i][1] = (f32x4){0.f, 0.f, 0.f, 0.f};
    }
  }
#pragma unroll
  for (int i = 0; i < 2; ++i) {
    const int r = g * 2 + i;
    f32x4 s0 = xa[i][0], s1 = xa[i][1];
    float ss = s0[0]*s0[0] + s0[1]*s0[1] + s0[2]*s0[2] + s0[3]*s0[3]
             + s1[0]*s1[0] + s1[1]*s1[1] + s1[2]*s1[2] + s1[3]*s1[3];
    ss += __shfl_xor(ss, 1);
    ss += __shfl_xor(ss, 2);
    ss += __shfl_xor(ss, 4);
    ss += __shfl_xor(ss, 8);
    float nrm = sqrtf(ss);
    float nc = fminf(fmaxf(nrm, 1e-8f), 1.0f - 1e-5f);
    float sc = atanhf(nc) / nc;
    s0 *= sc;
    s1 *= sc;
    uint4 pk;
    pk.x = (unsigned)f2bf(s0[0]) | ((unsigned)f2bf(s0[1]) << 16);
    pk.y = (unsigned)f2bf(s0[2]) | ((unsigned)f2bf(s0[3]) << 16);
    pk.z = (unsigned)f2bf(s1[0]) | ((unsigned)f2bf(s1[1]) << 16);
    pk.w = (unsigned)f2bf(s1[2]) | ((unsigned)f2bf(s1[3]) << 16);
    *(uint4*)((unsigned*)As + r * 68 + n15 * 4) = pk;
  }
  __syncthreads();

  // ---- layer 1 ----
  float bc[4];
#pragma unroll
  for (int c = 0; c < 4; ++c) bc[c] = ba[ct * 64 + c * 16 + n15];
  f32x4 acc[4];
#pragma unroll
  for (int c = 0; c < 4; ++c) acc[c] = (f32x4){0.f, 0.f, 0.f, 0.f};
  const int abase = (rt * 16 + n15) * 136 + q * 8;  // A[m=n15][k=q*8+j]
  short8 bfr[16];
#pragma unroll
  for (int s = 0; s < 4; ++s)
#pragma unroll
    for (int c = 0; c < 4; ++c)
      bfr[s * 4 + c] =
          *(const short8*)&Pa[(size_t)(((((ct << 2) | c) << 2) | s) * 64 + lane) * 8];
  short8 afr[4];
#pragma unroll
  for (int s = 0; s < 4; ++s) afr[s] = *(const short8*)&As[abase + s * 32];
#pragma unroll
  for (int s = 0; s < 4; ++s)
#pragma unroll
    for (int c = 0; c < 4; ++c)
      acc[c] = __builtin_amdgcn_mfma_f32_16x16x32_bf16(afr[s], bfr[s * 4 + c],
                                                       acc[c], 0, 0, 0);
  __syncthreads();

  // relu + bias -> As (C/D: row = rt*16 + q*4 + rr, col = ct*64 + c*16 + n15)
#pragma unroll
  for (int c = 0; c < 4; ++c)
#pragma unroll
    for (int rr = 0; rr < 4; ++rr) {
      float v = fmaxf(acc[c][rr] + bc[c], 0.f);
      As[(rt * 16 + q * 4 + rr) * 136 + ct * 64 + c * 16 + n15] = f2bf(v);
    }
  __syncthreads();

  // ---- layer 2 ----
#pragma unroll
  for (int c = 0; c < 4; ++c) bc[c] = bb[ct * 64 + c * 16 + n15];
#pragma unroll
  for (int c = 0; c < 4; ++c) acc[c] = (f32x4){0.f, 0.f, 0.f, 0.f};
#pragma unroll
  for (int s = 0; s < 4; ++s)
#pragma unroll
    for (int c = 0; c < 4; ++c)
      bfr[s * 4 + c] =
          *(const short8*)&Pb[(size_t)(((((ct << 2) | c) << 2) | s) * 64 + lane) * 8];
#pragma unroll
  for (int s = 0; s < 4; ++s) afr[s] = *(const short8*)&As[abase + s * 32];
#pragma unroll
  for (int s = 0; s < 4; ++s)
#pragma unroll
    for (int c = 0; c < 4; ++c)
      acc[c] = __builtin_amdgcn_mfma_f32_16x16x32_bf16(afr[s], bfr[s * 4 + c],
                                                       acc[c], 0, 0, 0);

  // write bf16 node_msg via LDS repack -> coalesced 16B stores
  __syncthreads();
#pragma unroll
  for (int c = 0; c < 4; ++c)
#pragma unroll
    for (int rr = 0; rr < 4; ++rr)
      As[(rt * 16 + q * 4 + rr) * 136 + ct * 64 + c * 16 + n15] =
          f2bf(acc[c][rr] + bc[c]);
  __syncthreads();
#pragma unroll
  for (int k = 0; k < 2; ++k) {  // 32 rows x 16 chunks = 512 units / 256 thr
    int u = tid + k * 256;
    int r = u >> 4, ch = u & 15;
    int grow = row0 + r;
    if (grow < N)
      *(short8*)(node_msg + (size_t)grow * DD + ch * 8) =
          *(const short8*)&As[r * 136 + ch * 8];
  }
}

// stage2: 1 wave / 16 rows / block (R17 structure). Replicated gather + mean
// -> MLP2 -> expmap0 -> out. q=lane>>4 (rows q*4..+3), n15=lane&15.
__global__ __launch_bounds__(64) void k_stage2(
    const unsigned short* __restrict__ node_msg, const int* __restrict__ degv8,
    const int* __restrict__ degS, const unsigned short* __restrict__ ebuf8,
    const unsigned short* __restrict__ ebufS, const unsigned short* __restrict__ Pa,
    const float* __restrict__ ba, const unsigned short* __restrict__ Pb,
    const float* __restrict__ bb, float* __restrict__ out, int N) {
  __shared__ unsigned short As[16 * 136];
  const int lane = threadIdx.x;  // 0..63
  const int q = lane >> 4;
  const int n15 = lane & 15;
  const int row0 = blockIdx.x * 16;

#pragma unroll
  for (int i = 0; i < 4; ++i) {
    const int r = q * 4 + i;
    const int grow = row0 + r;
    f32x4 s0 = {0.f, 0.f, 0.f, 0.f}, s1 = {0.f, 0.f, 0.f, 0.f};
    f32x4 t0 = {0.f, 0.f, 0.f, 0.f}, t1 = {0.f, 0.f, 0.f, 0.f};
    if (grow < N) {
      // metadata: 8 counts + spill count + 8 windows, all parallel loads
      int d8[NR];
#pragma unroll
      for (int rg = 0; rg < NR; ++rg) d8[rg] = degv8[(size_t)rg * N + grow];
      const int ds = degS[grow];
      u16x8 w[NR];
#pragma unroll
      for (int rg = 0; rg < NR; ++rg)
        w[rg] = *(const u16x8*)(ebuf8 + ((size_t)rg * N + grow) * CAP8);
      int dtot = 0;
#pragma unroll
      for (int rg = 0; rg < NR; ++rg) dtot += d8[rg];

      // gather: two halves of 4 replicas, 16 fixed slots in flight each
#pragma unroll
      for (int h = 0; h < 2; ++h) {
        short8 v[16];
#pragma unroll
        for (int rg4 = 0; rg4 < 4; ++rg4) {
          const int rg = h * 4 + rg4;
#pragma unroll
          for (int t = 0; t < 4; ++t) {
            int sidx = (t < d8[rg]) ? (int)w[rg][t] : 0;  // poison -> row 0
            v[rg4 * 4 + t] =
                *(const short8*)(node_msg + (size_t)sidx * DD + n15 * 8);
          }
        }
#pragma unroll
        for (int rg4 = 0; rg4 < 4; ++rg4) {
          const int rg = h * 4 + rg4;
#pragma unroll
          for (int t = 0; t < 4; ++t) {
            if (t < d8[rg]) {
              const short8 vv = v[rg4 * 4 + t];
#pragma unroll
              for (int j = 0; j < 4; ++j) {
                if (t & 1) {
                  t0[j] += bf2f(vv[j]);
                  t1[j] += bf2f(vv[j + 4]);
                } else {
                  s0[j] += bf2f(vv[j]);
                  s1[j] += bf2f(vv[j + 4]);
                }
              }
            }
          }
        }
        // window tail: slots 4..7 (P(deg_rg>4) ~ 2%), indices from REGISTERS
#pragma unroll
        for (int rg4 = 0; rg4 < 4; ++rg4) {
          const int rg = h * 4 + rg4;
          const int dl = (d8[rg] < CAP8) ? d8[rg] : CAP8;
          if (dl > 4) {
#pragma unroll
            for (int t = 4; t < 8; ++t) {
              if (t < dl) {
                short8 va = *(const short8*)(node_msg +
                                             (size_t)w[rg][t] * DD + n15 * 8);
#pragma unroll
                for (int j = 0; j < 4; ++j) {
                  s0[j] += bf2f(va[j]);
                  s1[j] += bf2f(va[j + 4]);
                }
              }
            }
          }
        }
      }
      // global spill (ultra-rare overflow path, exact)
      if (ds > 0) {
        const int dls = (ds < CAPS) ? ds : CAPS;
        const unsigned short* eb = ebufS + (size_t)grow * CAPS;
        for (int t = 0; t < dls; ++t) {
          short8 va = *(const short8*)(node_msg + (size_t)eb[t] * DD + n15 * 8);
#pragma unroll
          for (int j = 0; j < 4; ++j) {
            s0[j] += bf2f(va[j]);
            s1[j] += bf2f(va[j + 4]);
          }
        }
      }
      s0 += t0;
      s1 += t1;
      float inv = 1.f / ((float)dtot + 1e-8f);  // mean (count + EPS)
      s0 *= inv;
      s1 *= inv;
    }
    uint4 pk;
    pk.x = (unsigned)f2bf(s0[0]) | ((unsigned)f2bf(s0[1]) << 16);
    pk.y = (unsigned)f2bf(s0[2]) | ((unsigned)f2bf(s0[3]) << 16);
    pk.z = (unsigned)f2bf(s1[0]) | ((unsigned)f2bf(s1[1]) << 16);
    pk.w = (unsigned)f2bf(s1[2]) | ((unsigned)f2bf(s1[3]) << 16);
    *(uint4*)((unsigned*)As + r * 68 + n15 * 4) = pk;
  }
  __syncthreads();  // single wave: cheap s_barrier + waitcnt

  // ---- layer 1: 16 rows x 128 cols in one wave (8 col-frags) ----
  float bc[8];
#pragma unroll
  for (int cc = 0; cc < 8; ++cc) bc[cc] = ba[cc * 16 + n15];
  f32x4 acc[8];
#pragma unroll
  for (int cc = 0; cc < 8; ++cc) acc[cc] = (f32x4){0.f, 0.f, 0.f, 0.f};
  const int abase = n15 * 136 + q * 8;  // A[row=n15][k=q*8+j]
  short8 afr[4];
#pragma unroll
  for (int s = 0; s < 4; ++s) afr[s] = *(const short8*)&As[abase + s * 32];
#pragma unroll
  for (int s = 0; s < 4; ++s)
#pragma unroll
    for (int cc = 0; cc < 8; ++cc) {
      short8 b = *(const short8*)&Pa[(size_t)((cc * 4 + s) * 64 + lane) * 8];
      acc[cc] = __builtin_amdgcn_mfma_f32_16x16x32_bf16(afr[s], b, acc[cc], 0, 0, 0);
    }
  __syncthreads();

  // relu + bias -> As (C/D: row = q*4 + rr, col = cc*16 + n15)
#pragma unroll
  for (int cc = 0; cc < 8; ++cc)
#pragma unroll
    for (int rr = 0; rr < 4; ++rr) {
      float v = fmaxf(acc[cc][rr] + bc[cc], 0.f);
      As[(q * 4 + rr) * 136 + cc * 16 + n15] = f2bf(v);
    }
  __syncthreads();

  // ---- layer 2 ----
#pragma unroll
  for (int cc = 0; cc < 8; ++cc) bc[cc] = bb[cc * 16 + n15];
#pragma unroll
  for (int cc = 0; cc < 8; ++cc) acc[cc] = (f32x4){0.f, 0.f, 0.f, 0.f};
#pragma unroll
  for (int s = 0; s < 4; ++s) afr[s] = *(const short8*)&As[abase + s * 32];
#pragma unroll
  for (int s = 0; s < 4; ++s)
#pragma unroll
    for (int cc = 0; cc < 8; ++cc) {
      short8 b = *(const short8*)&Pb[(size_t)((cc * 4 + s) * 64 + lane) * 8];
      acc[cc] = __builtin_amdgcn_mfma_f32_16x16x32_bf16(afr[s], b, acc[cc], 0, 0, 0);
    }

  // ---- expmap0 epilogue: row q*4+rr fully within this 16-lane group ----
#pragma unroll
  for (int rr = 0; rr < 4; ++rr) {
    float vv[8];
    float ssq = 0.f;
#pragma unroll
    for (int cc = 0; cc < 8; ++cc) {
      vv[cc] = acc[cc][rr] + bc[cc];
      ssq += vv[cc] * vv[cc];
    }
    ssq += __shfl_xor(ssq, 1);
    ssq += __shfl_xor(ssq, 2);
    ssq += __shfl_xor(ssq, 4);
    ssq += __shfl_xor(ssq, 8);
    float nrm = sqrtf(ssq);
    float nc = fmaxf(nrm, 1e-8f);
    float sc = tanhf(nc) / nc;
    int grow = row0 + q * 4 + rr;
    if (grow < N) {
#pragma unroll
      for (int cc = 0; cc < 8; ++cc)
        __builtin_nontemporal_store(
            vv[cc] * sc, out + (size_t)grow * DD + cc * 16 + n15);
    }
  }
}

extern "C" void kernel_launch(void* const* d_in, const int* in_sizes, int n_in,
                              void* d_out, int out_size, void* d_ws, size_t ws_size,
                              hipStream_t stream) {
  const float* x = (const float*)d_in[0];
  const int* ei = (const int*)d_in[1];
  const float* w1 = (const float*)d_in[2];
  const float* b1 = (const float*)d_in[3];
  const float* w2 = (const float*)d_in[4];
  const float* b2 = (const float*)d_in[5];
  const float* w3 = (const float*)d_in[6];
  const float* b3 = (const float*)d_in[7];
  const float* w4 = (const float*)d_in[8];
  const float* b4 = (const float*)d_in[9];
  const int N = in_sizes[0] / DD;
  const int E = in_sizes[1] / 2;
  const int nf = (N + 31) / 32;
  const int nf2 = (N + 15) / 16;
  const int ne = (E + 1023) / 1024;  // 4 edges/thread, 1024/block

  // ws carve: node_msg[N*128 bf16] | degv8[8N int] | degS[N int] |
  //           ebuf8[8N*CAP8 u16] | ebufS[N*CAPS u16] | P[4*16384 bf16]
  unsigned short* node_msg = (unsigned short*)d_ws;
  int* degv8 = (int*)(node_msg + (size_t)N * DD);
  int* degS = degv8 + (size_t)NR * N;
  unsigned short* ebuf8 = (unsigned short*)(degS + N);
  unsigned short* ebufS = ebuf8 + (size_t)NR * N * CAP8;
  uintptr_t pw = (uintptr_t)(ebufS + (size_t)N * CAPS);
  pw = (pw + 63) & ~(uintptr_t)63;
  unsigned short* P = (unsigned short*)pw;
  float* outp = (float*)d_out;

  hipLaunchKernelGGL(k_init, dim3(32 + (9 * N + 255) / 256), dim3(256), 0,
                     stream, w1, w2, w3, w4, P, degv8, N);
  hipLaunchKernelGGL(k_stage1, dim3(ne + nf), dim3(256), 0, stream,
                     x, ei, P, b1, P + 16384, b2, node_msg, degv8, degS,
                     ebuf8, ebufS, N, E, ne);
  hipLaunchKernelGGL(k_stage2, dim3(nf2), dim3(64), 0, stream,
                     node_msg, degv8, degS, ebuf8, ebufS,
                     P + 2 * 16384, b3, P + 3 * 16384, b4, outp, N);
}

// Round 11
// 151.028 us; speedup vs baseline: 1.1180x; 1.1180x over previous
//
#include <hip/hip_runtime.h>
#include <hip/hip_bf16.h>

// HyperbolicMessagePassing: N=50000, E=600000, D=128.
// out = expmap0( MLP2( mean_scatter( MLP1(logmap0(x))[src] -> dst ) ) )
// R20 = R17 MLP/stage2 (proven best) + bucketed counting-sort CSR build:
//   R13/R16/R19 proved 600k random device-scope atomics+scattered stores are
//   a memory-side RMW-throughput wall (~40us) that requestor locality can't
//   fix. Replace with: k_scatter (LDS histogram -> 1 atomic per
//   block x bucket -> contiguous packed writes into 196 bucket regions) +
//   k_build (per-bucket LDS-atomic ranking -> ebuf/degv, fused with MLP).
//   CSR output format identical to R17; stage2 untouched.

#define DD 128
#define CAP 64   // padded-CSR slots per node
#define DS 16    // degv stride in ints (64B line per counter)
#define NB 196   // dst buckets (dst>>8, 50000/256)
#define BCAP 4096  // edges per bucket region (mean 3061, 19 sigma headroom)

typedef __attribute__((ext_vector_type(8))) short short8;
typedef __attribute__((ext_vector_type(8))) unsigned short u16x8;
typedef __attribute__((ext_vector_type(4))) unsigned short u16x4;
typedef __attribute__((ext_vector_type(4))) float f32x4;

__device__ __forceinline__ unsigned short f2bf(float f) {
  unsigned u = __float_as_uint(f);
  u += 0x7fffu + ((u >> 16) & 1u);  // round-to-nearest-even
  return (unsigned short)(u >> 16);
}
__device__ __forceinline__ float bf2f(short h) {
  return __uint_as_float(((unsigned)(unsigned short)h) << 16);
}

// blocks [0,32): pack 4 W (fp32 128x128) into bf16 MFMA B-frag-linear order:
//   P[m*16384 + ((cc*4+s)*64 + lane)*8 + j]
//     = bf16(W[(s*32+(lane>>4)*8+j)*128 + cc*16+(lane&15)])
// blocks [32,..): zero bcur[NB*16]
__global__ void k_init(const float* __restrict__ w1, const float* __restrict__ w2,
                       const float* __restrict__ w3, const float* __restrict__ w4,
                       unsigned short* __restrict__ P, int* __restrict__ bcur) {
  if (blockIdx.x < 32) {
    int idx = blockIdx.x * 256 + threadIdx.x;  // 4 matrices x 2048 (frag,lane)
    int m = idx >> 11;
    int id = idx & 2047;
    int f = id >> 6, l = id & 63;
    int cc = f >> 2, s = f & 3, q = l >> 4, n15 = l & 15;
    const float* W = (m == 0) ? w1 : (m == 1) ? w2 : (m == 2) ? w3 : w4;
    const float* wp = W + (s * 32 + q * 8) * DD + cc * 16 + n15;
    unsigned short* op = P + (size_t)m * 16384 + (size_t)id * 8;
#pragma unroll
    for (int j = 0; j < 8; ++j) op[j] = f2bf(wp[j * DD]);
  } else {
    int i = (blockIdx.x - 32) * 256 + threadIdx.x;
    if (i < NB * 16) bcur[i] = 0;
  }
}

// k_scatter: bucketize edges. 1024 edges/block. LDS histogram -> one global
// atomic per (block,bucket) claims a contiguous range -> packed u32 writes.
__global__ __launch_bounds__(256) void k_scatter(
    const int* __restrict__ ei, int* __restrict__ bcur,
    unsigned* __restrict__ bedge, int E) {
  __shared__ int cnt[NB], base[NB], cur[NB];
  const int tid = threadIdx.x;
  if (tid < NB) {
    cnt[tid] = 0;
    cur[tid] = 0;
  }
  __syncthreads();
  int d_[4], s_[4];
  bool ok[4];
#pragma unroll
  for (int k = 0; k < 4; ++k) {
    int e = blockIdx.x * 1024 + k * 256 + tid;
    ok[k] = (e < E);
    if (ok[k]) {
      d_[k] = ei[e];       // edge_index[0] = dst
      s_[k] = ei[E + e];   // edge_index[1] = src
      atomicAdd(&cnt[d_[k] >> 8], 1);
    }
  }
  __syncthreads();
  if (tid < NB) base[tid] = atomicAdd(bcur + tid * 16, cnt[tid]);
  __syncthreads();
#pragma unroll
  for (int k = 0; k < 4; ++k)
    if (ok[k]) {
      int bk = d_[k] >> 8;
      int r = atomicAdd(&cur[bk], 1);
      int pos = base[bk] + r;
      if (pos < BCAP)
        bedge[(size_t)bk * BCAP + pos] =
            ((unsigned)d_[k] << 16) | (unsigned)s_[k];
    }
}

// k_build: blocks [0,NB) = per-bucket CSR build (LDS-atomic per-dst ranks ->
// ebuf u16 + exact degv, all nodes covered); blocks [NB,..) = logmap0 + MLP1
// -> node_msg (identical to R17 stage1 MLP part).
__global__ __launch_bounds__(256) void k_build(
    const float* __restrict__ x, const unsigned short* __restrict__ Pa,
    const float* __restrict__ ba, const unsigned short* __restrict__ Pb,
    const float* __restrict__ bb, unsigned short* __restrict__ node_msg,
    const unsigned* __restrict__ bedge, const int* __restrict__ bcur,
    int* __restrict__ degv, unsigned short* __restrict__ ebuf, int N) {
  const int tid = threadIdx.x;

  if (blockIdx.x < NB) {  // ---- bucket CSR build ----
    __shared__ int cnt[256];
    const int b = blockIdx.x;
    cnt[tid] = 0;
    __syncthreads();
    int tot = bcur[b * 16];
    if (tot > BCAP) tot = BCAP;
    for (int i = tid; i < tot; i += 256) {
      unsigned p = bedge[(size_t)b * BCAP + i];
      int d = (int)(p >> 16);
      int s = (int)(p & 0xffffu);
      int r = atomicAdd(&cnt[d & 255], 1);
      if (r < CAP) ebuf[(size_t)d * CAP + r] = (unsigned short)s;
    }
    __syncthreads();
    int d = (b << 8) + tid;
    if (d < N) degv[(size_t)d * DS] = cnt[tid];
    return;
  }

  // ---- MLP: logmap0 + 2-layer -> node_msg (R17 verbatim) ----
  __shared__ unsigned short As[32 * 136];  // row stride 136 shorts
  const int lane = tid & 63;
  const int wv = tid >> 6;  // 0..3
  const int rt = wv >> 1;   // row-tile 0..1
  const int ct = wv & 1;    // col-tile 0..1
  const int q = lane >> 4;
  const int n15 = lane & 15;
  const int row0 = (blockIdx.x - NB) * 32;
  const int g = (wv << 2) | q;  // staging group 0..15

  f32x4 xa[2][2];
#pragma unroll
  for (int i = 0; i < 2; ++i) {
    const int grow = row0 + g * 2 + i;
    if (grow < N) {
      const f32x4* p = (const f32x4*)(x + (size_t)grow * DD + n15 * 8);
      xa[i][0] = p[0];
      xa[i][1] = p[1];
    } else {
      xa[i][0] = (f32x4){0.f, 0.f, 0.f, 0.f};
      xa[i][1] = (f32x4){0.f, 0.f, 0.f, 0.f};
    }
  }
#pragma unroll
  for (int i = 0; i < 2; ++i) {
    const int r = g * 2 + i;
    f32x4 s0 = xa[i][0], s1 = xa[i][1];
    float ss = s0[0]*s0[0] + s0[1]*s0[1] + s0[2]*s0[2] + s0[3]*s0[3]
             + s1[0]*s1[0] + s1[1]*s1[1] + s1[2]*s1[2] + s1[3]*s1[3];
    ss += __shfl_xor(ss, 1);
    ss += __shfl_xor(ss, 2);
    ss += __shfl_xor(ss, 4);
    ss += __shfl_xor(ss, 8);
    float nrm = sqrtf(ss);
    float nc = fminf(fmaxf(nrm, 1e-8f), 1.0f - 1e-5f);
    float sc = atanhf(nc) / nc;
    s0 *= sc;
    s1 *= sc;
    uint4 pk;
    pk.x = (unsigned)f2bf(s0[0]) | ((unsigned)f2bf(s0[1]) << 16);
    pk.y = (unsigned)f2bf(s0[2]) | ((unsigned)f2bf(s0[3]) << 16);
    pk.z = (unsigned)f2bf(s1[0]) | ((unsigned)f2bf(s1[1]) << 16);
    pk.w = (unsigned)f2bf(s1[2]) | ((unsigned)f2bf(s1[3]) << 16);
    *(uint4*)((unsigned*)As + r * 68 + n15 * 4) = pk;
  }
  __syncthreads();

  // layer 1
  float bc[4];
#pragma unroll
  for (int c = 0; c < 4; ++c) bc[c] = ba[ct * 64 + c * 16 + n15];
  f32x4 acc[4];
#pragma unroll
  for (int c = 0; c < 4; ++c) acc[c] = (f32x4){0.f, 0.f, 0.f, 0.f};
  const int abase = (rt * 16 + n15) * 136 + q * 8;  // A[m=n15][k=q*8+j]
  short8 bfr[16];
#pragma unroll
  for (int s = 0; s < 4; ++s)
#pragma unroll
    for (int c = 0; c < 4; ++c)
      bfr[s * 4 + c] =
          *(const short8*)&Pa[(size_t)(((((ct << 2) | c) << 2) | s) * 64 + lane) * 8];
  short8 afr[4];
#pragma unroll
  for (int s = 0; s < 4; ++s) afr[s] = *(const short8*)&As[abase + s * 32];
#pragma unroll
  for (int s = 0; s < 4; ++s)
#pragma unroll
    for (int c = 0; c < 4; ++c)
      acc[c] = __builtin_amdgcn_mfma_f32_16x16x32_bf16(afr[s], bfr[s * 4 + c],
                                                       acc[c], 0, 0, 0);
  __syncthreads();

#pragma unroll
  for (int c = 0; c < 4; ++c)
#pragma unroll
    for (int rr = 0; rr < 4; ++rr) {
      float v = fmaxf(acc[c][rr] + bc[c], 0.f);
      As[(rt * 16 + q * 4 + rr) * 136 + ct * 64 + c * 16 + n15] = f2bf(v);
    }
  __syncthreads();

  // layer 2
#pragma unroll
  for (int c = 0; c < 4; ++c) bc[c] = bb[ct * 64 + c * 16 + n15];
#pragma unroll
  for (int c = 0; c < 4; ++c) acc[c] = (f32x4){0.f, 0.f, 0.f, 0.f};
#pragma unroll
  for (int s = 0; s < 4; ++s)
#pragma unroll
    for (int c = 0; c < 4; ++c)
      bfr[s * 4 + c] =
          *(const short8*)&Pb[(size_t)(((((ct << 2) | c) << 2) | s) * 64 + lane) * 8];
#pragma unroll
  for (int s = 0; s < 4; ++s) afr[s] = *(const short8*)&As[abase + s * 32];
#pragma unroll
  for (int s = 0; s < 4; ++s)
#pragma unroll
    for (int c = 0; c < 4; ++c)
      acc[c] = __builtin_amdgcn_mfma_f32_16x16x32_bf16(afr[s], bfr[s * 4 + c],
                                                       acc[c], 0, 0, 0);

  __syncthreads();
#pragma unroll
  for (int c = 0; c < 4; ++c)
#pragma unroll
    for (int rr = 0; rr < 4; ++rr)
      As[(rt * 16 + q * 4 + rr) * 136 + ct * 64 + c * 16 + n15] =
          f2bf(acc[c][rr] + bc[c]);
  __syncthreads();
#pragma unroll
  for (int k = 0; k < 2; ++k) {  // 32 rows x 16 chunks = 512 units / 256 thr
    int u = tid + k * 256;
    int r = u >> 4, ch = u & 15;
    int grow = row0 + r;
    if (grow < N)
      *(short8*)(node_msg + (size_t)grow * DD + ch * 8) =
          *(const short8*)&As[r * 136 + ch * 8];
  }
}

// stage2: 1 wave / 16 rows / block (R17 verbatim). Gather + mean -> MLP2 ->
// expmap0 -> out. lane: q=lane>>4 (rows q*4..q*4+3), n15=lane&15 (col chunk).
__global__ __launch_bounds__(64) void k_stage2(
    const unsigned short* __restrict__ node_msg, const int* __restrict__ degv,
    const unsigned short* __restrict__ ebuf, const unsigned short* __restrict__ Pa,
    const float* __restrict__ ba, const unsigned short* __restrict__ Pb,
    const float* __restrict__ bb, float* __restrict__ out, int N) {
  __shared__ unsigned short As[16 * 136];
  const int lane = threadIdx.x;  // 0..63
  const int q = lane >> 4;
  const int n15 = lane & 15;
  const int row0 = blockIdx.x * 16;

#pragma unroll
  for (int i = 0; i < 4; ++i) {
    const int r = q * 4 + i;
    const int grow = row0 + r;
    f32x4 s0 = {0.f, 0.f, 0.f, 0.f}, s1 = {0.f, 0.f, 0.f, 0.f};
    if (grow < N) {
      const int d = degv[(size_t)grow * DS];
      const int dl = (d < CAP) ? d : CAP;
      const unsigned short* eb = ebuf + (size_t)grow * CAP;
      u16x8 cA = *(const u16x8*)(eb);
      u16x8 cB = *(const u16x8*)(eb + 8);
      int id[16];
#pragma unroll
      for (int t = 0; t < 8; ++t) {
        id[t] = cA[t];
        id[t + 8] = cB[t];
      }
      short8 v[16];
#pragma unroll
      for (int t = 0; t < 16; ++t) {
        int sidx = (t < dl) ? id[t] : 0;  // clamp poison to a safe hot row
        v[t] = *(const short8*)(node_msg + (size_t)sidx * DD + n15 * 8);
      }
      f32x4 t0 = {0.f, 0.f, 0.f, 0.f}, t1 = {0.f, 0.f, 0.f, 0.f};
#pragma unroll
      for (int t = 0; t < 16; ++t) {
        if (t < dl) {
#pragma unroll
          for (int j = 0; j < 4; ++j) {
            if (t & 1) {
              t0[j] += bf2f(v[t][j]);
              t1[j] += bf2f(v[t][j + 4]);
            } else {
              s0[j] += bf2f(v[t][j]);
              s1[j] += bf2f(v[t][j + 4]);
            }
          }
        }
      }
      // tail: deg > 16 (~10% of rows), 4-deep
      int t = 16;
      for (; t + 3 < dl; t += 4) {
        u16x4 idx = *(const u16x4*)(eb + t);
        short8 v0 = *(const short8*)(node_msg + (size_t)idx[0] * DD + n15 * 8);
        short8 v1 = *(const short8*)(node_msg + (size_t)idx[1] * DD + n15 * 8);
        short8 v2 = *(const short8*)(node_msg + (size_t)idx[2] * DD + n15 * 8);
        short8 v3 = *(const short8*)(node_msg + (size_t)idx[3] * DD + n15 * 8);
#pragma unroll
        for (int j = 0; j < 4; ++j) {
          s0[j] += bf2f(v0[j]) + bf2f(v1[j]);
          s1[j] += bf2f(v0[j + 4]) + bf2f(v1[j + 4]);
          t0[j] += bf2f(v2[j]) + bf2f(v3[j]);
          t1[j] += bf2f(v2[j + 4]) + bf2f(v3[j + 4]);
        }
      }
      for (; t < dl; ++t) {
        int sa = eb[t];
        short8 va = *(const short8*)(node_msg + (size_t)sa * DD + n15 * 8);
#pragma unroll
        for (int j = 0; j < 4; ++j) {
          s0[j] += bf2f(va[j]);
          s1[j] += bf2f(va[j + 4]);
        }
      }
      s0 += t0;
      s1 += t1;
      float inv = 1.f / ((float)d + 1e-8f);  // mean (count + EPS)
      s0 *= inv;
      s1 *= inv;
    }
    uint4 pk;
    pk.x = (unsigned)f2bf(s0[0]) | ((unsigned)f2bf(s0[1]) << 16);
    pk.y = (unsigned)f2bf(s0[2]) | ((unsigned)f2bf(s0[3]) << 16);
    pk.z = (unsigned)f2bf(s1[0]) | ((unsigned)f2bf(s1[1]) << 16);
    pk.w = (unsigned)f2bf(s1[2]) | ((unsigned)f2bf(s1[3]) << 16);
    *(uint4*)((unsigned*)As + r * 68 + n15 * 4) = pk;
  }
  __syncthreads();  // single wave: cheap s_barrier + waitcnt

  // ---- layer 1: 16 rows x 128 cols in one wave (8 col-frags) ----
  float bc[8];
#pragma unroll
  for (int cc = 0; cc < 8; ++cc) bc[cc] = ba[cc * 16 + n15];
  f32x4 acc[8];
#pragma unroll
  for (int cc = 0; cc < 8; ++cc) acc[cc] = (f32x4){0.f, 0.f, 0.f, 0.f};
  const int abase = n15 * 136 + q * 8;  // A[row=n15][k=q*8+j]
  short8 afr[4];
#pragma unroll
  for (int s = 0; s < 4; ++s) afr[s] = *(const short8*)&As[abase + s * 32];
#pragma unroll
  for (int s = 0; s < 4; ++s)
#pragma unroll
    for (int cc = 0; cc < 8; ++cc) {
      short8 b = *(const short8*)&Pa[(size_t)((cc * 4 + s) * 64 + lane) * 8];
      acc[cc] = __builtin_amdgcn_mfma_f32_16x16x32_bf16(afr[s], b, acc[cc], 0, 0, 0);
    }
  __syncthreads();

#pragma unroll
  for (int cc = 0; cc < 8; ++cc)
#pragma unroll
    for (int rr = 0; rr < 4; ++rr) {
      float v = fmaxf(acc[cc][rr] + bc[cc], 0.f);
      As[(q * 4 + rr) * 136 + cc * 16 + n15] = f2bf(v);
    }
  __syncthreads();

  // ---- layer 2 ----
#pragma unroll
  for (int cc = 0; cc < 8; ++cc) bc[cc] = bb[cc * 16 + n15];
#pragma unroll
  for (int cc = 0; cc < 8; ++cc) acc[cc] = (f32x4){0.f, 0.f, 0.f, 0.f};
#pragma unroll
  for (int s = 0; s < 4; ++s) afr[s] = *(const short8*)&As[abase + s * 32];
#pragma unroll
  for (int s = 0; s < 4; ++s)
#pragma unroll
    for (int cc = 0; cc < 8; ++cc) {
      short8 b = *(const short8*)&Pb[(size_t)((cc * 4 + s) * 64 + lane) * 8];
      acc[cc] = __builtin_amdgcn_mfma_f32_16x16x32_bf16(afr[s], b, acc[cc], 0, 0, 0);
    }

  // ---- expmap0 epilogue: row q*4+rr fully within this 16-lane group ----
#pragma unroll
  for (int rr = 0; rr < 4; ++rr) {
    float vv[8];
    float ssq = 0.f;
#pragma unroll
    for (int cc = 0; cc < 8; ++cc) {
      vv[cc] = acc[cc][rr] + bc[cc];
      ssq += vv[cc] * vv[cc];
    }
    ssq += __shfl_xor(ssq, 1);
    ssq += __shfl_xor(ssq, 2);
    ssq += __shfl_xor(ssq, 4);
    ssq += __shfl_xor(ssq, 8);
    float nrm = sqrtf(ssq);
    float nc = fmaxf(nrm, 1e-8f);
    float sc = tanhf(nc) / nc;
    int grow = row0 + q * 4 + rr;
    if (grow < N) {
#pragma unroll
      for (int cc = 0; cc < 8; ++cc)
        __builtin_nontemporal_store(
            vv[cc] * sc, out + (size_t)grow * DD + cc * 16 + n15);
    }
  }
}

extern "C" void kernel_launch(void* const* d_in, const int* in_sizes, int n_in,
                              void* d_out, int out_size, void* d_ws, size_t ws_size,
                              hipStream_t stream) {
  const float* x = (const float*)d_in[0];
  const int* ei = (const int*)d_in[1];
  const float* w1 = (const float*)d_in[2];
  const float* b1 = (const float*)d_in[3];
  const float* w2 = (const float*)d_in[4];
  const float* b2 = (const float*)d_in[5];
  const float* w3 = (const float*)d_in[6];
  const float* b3 = (const float*)d_in[7];
  const float* w4 = (const float*)d_in[8];
  const float* b4 = (const float*)d_in[9];
  const int N = in_sizes[0] / DD;
  const int E = in_sizes[1] / 2;
  const int nf = (N + 31) / 32;
  const int nf2 = (N + 15) / 16;
  const int ne = (E + 1023) / 1024;  // 1024 edges/block for k_scatter

  // ws carve: node_msg[N*128 bf16] | degv[N*16 int] | ebuf[N*64 u16] |
  //           bedge[NB*BCAP u32] | bcur[NB*16 int] | P[4*16384 bf16]  ~25.8MB
  unsigned short* node_msg = (unsigned short*)d_ws;
  int* degv = (int*)(node_msg + (size_t)N * DD);
  unsigned short* ebuf = (unsigned short*)(degv + (size_t)N * DS);
  unsigned* bedge = (unsigned*)(ebuf + (size_t)N * CAP);
  int* bcur = (int*)(bedge + (size_t)NB * BCAP);
  uintptr_t pw = (uintptr_t)(bcur + NB * 16);
  pw = (pw + 63) & ~(uintptr_t)63;
  unsigned short* P = (unsigned short*)pw;
  float* outp = (float*)d_out;

  hipLaunchKernelGGL(k_init, dim3(32 + (NB * 16 + 255) / 256), dim3(256), 0,
                     stream, w1, w2, w3, w4, P, bcur);
  hipLaunchKernelGGL(k_scatter, dim3(ne), dim3(256), 0, stream,
                     ei, bcur, bedge, E);
  hipLaunchKernelGGL(k_build, dim3(NB + nf), dim3(256), 0, stream,
                     x, P, b1, P + 16384, b2, node_msg, bedge, bcur,
                     degv, ebuf, N);
  hipLaunchKernelGGL(k_stage2, dim3(nf2), dim3(64), 0, stream,
                     node_msg, degv, ebuf, P + 2 * 16384, b3, P + 3 * 16384, b4,
                     outp, N);
}